// Round 12
// baseline (134.601 us; speedup 1.0000x reference)
//
#include <hip/hip_runtime.h>
#include <hip/hip_bf16.h>
#include <cstdint>

#define B_ 2
#define S_ 2048
#define D_ 1024
#define H_ 16
#define DK_ 64
#define HALF_ 32   // DK/2

typedef short bf16x8 __attribute__((ext_vector_type(8)));
typedef float f32x4  __attribute__((ext_vector_type(4)));
typedef unsigned int u32;

static __device__ __forceinline__ unsigned short bfbits(float f) {
    __hip_bfloat16 h = __float2bfloat16(f);
    unsigned short u; __builtin_memcpy(&u, &h, 2); return u;
}
static __device__ __forceinline__ unsigned pack2bf(float a, float b) {
    return (unsigned)bfbits(a) | ((unsigned)bfbits(b) << 16);
}

// async 16B global->LDS (wave-uniform LDS base + lane*16; global addr per-lane)
static __device__ __forceinline__ void gload_lds16(const void* g, void* l) {
    __builtin_amdgcn_global_load_lds(
        (const __attribute__((address_space(1))) u32*)(uintptr_t)g,
        (__attribute__((address_space(3))) u32*)(uintptr_t)l,
        16, 0, 0);
}

// ---------------------------------------------------------------------------
// Kernel 0: fp32 -> bf16 conversion (x + 4 weights) and packed (cos,sin) table.
// ---------------------------------------------------------------------------
__global__ __launch_bounds__(256) void to_bf16_kernel(
    const float* __restrict__ x,
    const float* __restrict__ wq, const float* __restrict__ wk,
    const float* __restrict__ wv, const float* __restrict__ wo,
    const float* __restrict__ sin_tab, const float* __restrict__ cos_tab,
    __hip_bfloat16* __restrict__ xb,
    __hip_bfloat16* __restrict__ wqb, __hip_bfloat16* __restrict__ wkb,
    __hip_bfloat16* __restrict__ wvb, __hip_bfloat16* __restrict__ wob,
    float2* __restrict__ sctab)
{
    const int seg = blockIdx.y;   // 0..3 x quarters; 4..7 weights; 8 sincos
    if (seg == 8) {
        if (blockIdx.x >= 64) return;     // 65536 entries / 4 per thread
        size_t i = ((size_t)blockIdx.x * 256 + threadIdx.x) * 4;
        float4 c = *reinterpret_cast<const float4*>(cos_tab + i);
        float4 s = *reinterpret_cast<const float4*>(sin_tab + i);
        float4* dst = reinterpret_cast<float4*>(sctab + i);
        dst[0] = make_float4(c.x, s.x, c.y, s.y);
        dst[1] = make_float4(c.z, s.z, c.w, s.w);
        return;
    }
    const float* src;
    __hip_bfloat16* dst;
    size_t off = 0;
    if (seg < 4)       { src = x;  dst = xb;  off = (size_t)seg << 20; }
    else if (seg == 4) { src = wq; dst = wqb; }
    else if (seg == 5) { src = wk; dst = wkb; }
    else if (seg == 6) { src = wv; dst = wvb; }
    else               { src = wo; dst = wob; }
    size_t i = off + ((size_t)blockIdx.x * 256 + threadIdx.x) * 4;
    float4 v = *reinterpret_cast<const float4*>(src + i);
    ushort4 u = make_ushort4(bfbits(v.x), bfbits(v.y), bfbits(v.z), bfbits(v.w));
    *reinterpret_cast<ushort4*>(dst + i) = u;
}

// ---------------------------------------------------------------------------
// MFMA GEMM v2 (restored from round 10 — proven 43 us for QKV):
// C = A @ W^T, bf16 in, 16x16x32, 128x128 tile, BK=32, dbuf, XCD swizzle.
// MODE 0: QKV + RoPE epilogue; Q pre-scaled by 0.125*log2(e). MODE 1: out-proj.
// ---------------------------------------------------------------------------
template<int MODE>
__global__ __launch_bounds__(256) void mfma_gemm_kernel(
    const __hip_bfloat16* __restrict__ A,
    const __hip_bfloat16* __restrict__ Wq, const __hip_bfloat16* __restrict__ Wk,
    const __hip_bfloat16* __restrict__ Wv,
    __hip_bfloat16* __restrict__ out_q, __hip_bfloat16* __restrict__ out_k,
    __hip_bfloat16* __restrict__ out_v,
    float* __restrict__ out_f32,
    const float2* __restrict__ sctab,
    const int* __restrict__ tpos)
{
    constexpr int K = 1024;
    const int which = (MODE == 0) ? blockIdx.z : 3;
    const __hip_bfloat16* __restrict__ W =
        (MODE == 1) ? Wq : (which == 0 ? Wq : which == 1 ? Wk : Wv);

    __shared__ __align__(16) unsigned char As[2][128 * 4 * 16];  // 2 x 8 KB
    __shared__ __align__(16) unsigned char Bs[2][128 * 4 * 16];  // 2 x 8 KB

    const int tid = threadIdx.x;
    const int wid = tid >> 6;
    const int l   = tid & 63;
    const int g   = l >> 4;
    const int i16 = l & 15;
    const int wr  = wid >> 1, wc = wid & 1;

    const int wg   = blockIdx.x;
    const int tile = (wg & 7) * 32 + (wg >> 3);
    const int row0 = (tile >> 3) * 128;
    const int col0 = (tile & 7) * 128;

    const __hip_bfloat16* Abase = A + (size_t)row0 * K;
    const __hip_bfloat16* Wbase = W + (size_t)col0 * K;

    f32x4 acc[4][4];
    const f32x4 zero = {0.f, 0.f, 0.f, 0.f};
    #pragma unroll
    for (int mi = 0; mi < 4; ++mi)
        #pragma unroll
        for (int ni = 0; ni < 4; ++ni) acc[mi][ni] = zero;

    int a_off[4], b_off[4];
    #pragma unroll
    for (int f = 0; f < 4; ++f) {
        int ra = wr * 64 + f * 16 + i16;
        a_off[f] = (ra * 4 + (g ^ ((ra >> 1) & 3))) * 16;
        int rb = wc * 64 + f * 16 + i16;
        b_off[f] = (rb * 4 + (g ^ ((rb >> 1) & 3))) * 16;
    }

    int st_goff[2], st_loff[2];
    #pragma unroll
    for (int it = 0; it < 2; ++it) {
        int c = it * 256 + wid * 64 + l;
        int row = c >> 2;
        int kc = (c & 3) ^ ((row >> 1) & 3);
        st_goff[it] = row * K + kc * 8;
        st_loff[it] = (it * 256 + wid * 64) * 16;
    }

    #pragma unroll
    for (int it = 0; it < 2; ++it) {
        gload_lds16(Abase + st_goff[it], &As[0][0] + st_loff[it]);
        gload_lds16(Wbase + st_goff[it], &Bs[0][0] + st_loff[it]);
    }
    __syncthreads();

    for (int t = 0; t < K / 32; ++t) {
        const int cur = t & 1;
        if (t + 1 < K / 32) {
            const int k1 = (t + 1) * 32;
            #pragma unroll
            for (int it = 0; it < 2; ++it) {
                gload_lds16(Abase + k1 + st_goff[it], &As[cur ^ 1][0] + st_loff[it]);
                gload_lds16(Wbase + k1 + st_goff[it], &Bs[cur ^ 1][0] + st_loff[it]);
            }
        }
        bf16x8 af[4], bfr[4];
        #pragma unroll
        for (int f = 0; f < 4; ++f) {
            af[f]  = *reinterpret_cast<const bf16x8*>(&As[cur][0] + a_off[f]);
            bfr[f] = *reinterpret_cast<const bf16x8*>(&Bs[cur][0] + b_off[f]);
        }
        #pragma unroll
        for (int mi = 0; mi < 4; ++mi)
            #pragma unroll
            for (int ni = 0; ni < 4; ++ni)
                acc[mi][ni] = __builtin_amdgcn_mfma_f32_16x16x32_bf16(
                    af[mi], bfr[ni], acc[mi][ni], 0, 0, 0);
        __syncthreads();
    }

    if (MODE == 0) {
        __hip_bfloat16* __restrict__ outp =
            which == 0 ? out_q : which == 1 ? out_k : out_v;
        const int head = (col0 >> 6) + wc;
        #pragma unroll
        for (int mi = 0; mi < 4; ++mi) {
            #pragma unroll
            for (int r = 0; r < 4; ++r) {
                const int gi = row0 + wr * 64 + mi * 16 + g * 4 + r;
                const int b_ = gi >> 11;
                const int s_ = gi & (S_ - 1);
                const int pos = tpos[gi];
                const float2* sc = sctab + pos * HALF_;
                __hip_bfloat16* orow =
                    outp + (((size_t)b_ * H_ + head) * S_ + s_) * DK_;
                #pragma unroll
                for (int ni = 0; ni < 4; ++ni) {
                    float val = acc[mi][ni][r];
                    float other = __shfl_xor(val, 1, 64);
                    const int dk = ni * 16 + i16;
                    float res;
                    if (which < 2) {
                        float2 cs = sc[ni * 8 + (i16 >> 1)];
                        res = (i16 & 1) ? fmaf(cs.y, other, cs.x * val)
                                        : (cs.x * val - cs.y * other);
                    } else {
                        res = val;
                    }
                    // 0.125 * log2(e): softmax runs in exp2 domain
                    if (which == 0) res *= 0.180336880f;
                    orow[dk] = __float2bfloat16(res);
                }
            }
        }
    } else {
        #pragma unroll
        for (int mi = 0; mi < 4; ++mi) {
            #pragma unroll
            for (int r = 0; r < 4; ++r) {
                const int gi = row0 + wr * 64 + mi * 16 + g * 4 + r;
                float* orow = out_f32 + (size_t)gi * D_ + col0 + wc * 64;
                #pragma unroll
                for (int ni = 0; ni < 4; ++ni)
                    orow[ni * 16 + i16] = acc[mi][ni][r];
            }
        }
    }
}

// ---------------------------------------------------------------------------
// Kernel 2 (v8): causal flash attention, bf16 MFMA 16x16x32.
//  Base = round-10 structure (QBLK=64, 4 waves, 1024 blocks, balanced swizzle,
//  shfl-free steady state, deferred l-reduction). ONE change: counted-vmcnt
//  tile barrier (T4) with 2-deep K prefetch (3 LDS buffers).
//   - iter t: issue V(t+1) reg-loads FIRST, then K(t+2) gload_lds;
//     compute tile t; scatter V(t+1) (compiler waits vmcnt(2) for V regs,
//     K(t+2) stays in flight); then {s_waitcnt vmcnt(2) lgkmcnt(0); s_barrier}.
//   - invariant: at barrier B_{t-1} each wave's only outstanding VMEM is
//     K(t+1) -> K(t) (issued at iter t-2) has landed for ALL waves before
//     any wave reads it at iter t. V double-buffer windows disjoint.
//  LDS 48 KB -> 3 blocks/CU.
// ---------------------------------------------------------------------------
__global__ __launch_bounds__(256) void flash_mfma_kernel(
    const __hip_bfloat16* __restrict__ q,   // (b,h,s,dk), pre-scaled
    const __hip_bfloat16* __restrict__ k,
    const __hip_bfloat16* __restrict__ v,
    __hip_bfloat16* __restrict__ attn)      // (b,s,D) bf16
{
    __shared__ __align__(16) unsigned char Ks[3][64 * 128];  // 24 KB (tri-buf)
    __shared__ __align__(16) unsigned char Vt[2][64 * 128];  // 16 KB
    __shared__ __align__(16) unsigned char Ps[4][16 * 128];  //  8 KB

    const int tid = threadIdx.x;
    const int w   = tid >> 6;        // 0..3
    const int l   = tid & 63;
    const int g   = l >> 4;
    const int i16 = l & 15;

    // balanced block swizzle: per-XCD bh locality; each CU's 4 blocks
    // (idx = r*32 + c, r=0..3) get qsb = {31-c, c, 31-c, c} -> 66 tiles total
    const int wgid = blockIdx.x;              // 0..1023
    const int xcd  = wgid & 7;
    const int idx  = wgid >> 3;               // 0..127
    const int r_   = idx >> 5;                // 0..3
    const int c_   = idx & 31;                // 0..31
    const int bh   = xcd * 4 + r_;
    const int qsb  = (r_ & 1) ? c_ : (31 - c_);

    const size_t base = (size_t)bh * S_ * DK_;
    const __hip_bfloat16* kb_ = k + base;
    const __hip_bfloat16* vb_ = v + base;
    const int nt = qsb + 1;

    // K staging geometry: 512 chunks of 16B, 2 per thread (linear LDS dest,
    // inverse swizzle folded into global source)
    int ksrc[2], kdst[2];
    #pragma unroll
    for (int it = 0; it < 2; ++it) {
        int c = it * 256 + tid;
        int krow = c >> 3;
        int kchunk = (c & 7) ^ (krow & 7);
        ksrc[it] = krow * DK_ + kchunk * 8;
        kdst[it] = c * 16;
    }
    // V staging: per-lane row j=l, wave-constant d8 (conflict-free, 2-way)
    const int vd8_0 = w;        // it = 0
    const int vd8_1 = 4 + w;    // it = 1
    unsigned char* const pw = &Ps[w][0];

    const int qrow = qsb * 64 + w * 16 + i16;  // this lane's q-row

    // Q fragments in registers
    bf16x8 qf0, qf1;
    {
        const __hip_bfloat16* qp = q + base + (size_t)qrow * DK_ + g * 8;
        qf0 = *reinterpret_cast<const bf16x8*>(qp);
        qf1 = *reinterpret_cast<const bf16x8*>(qp + 32);
    }

    f32x4 o[4] = {};
    float m_run = -1e30f, l_run = 0.0f;   // l_run = per-lane partial

    // prologue: stage K(0) -> Ks[0], K(1) -> Ks[1]; V(0) -> Vt[0]; full drain
    #pragma unroll
    for (int it = 0; it < 2; ++it)
        gload_lds16(kb_ + ksrc[it], &Ks[0][0] + kdst[it]);
    if (nt > 1) {
        #pragma unroll
        for (int it = 0; it < 2; ++it)
            gload_lds16(kb_ + 64 * DK_ + ksrc[it], &Ks[1][0] + kdst[it]);
    }
    {
        float4 vv0 = *reinterpret_cast<const float4*>(vb_ + l * DK_ + vd8_0 * 8);
        float4 vv1 = *reinterpret_cast<const float4*>(vb_ + l * DK_ + vd8_1 * 8);
        const unsigned short* u0 = reinterpret_cast<const unsigned short*>(&vv0);
        const unsigned short* u1 = reinterpret_cast<const unsigned short*>(&vv1);
        #pragma unroll
        for (int s = 0; s < 8; ++s) {
            int d0 = vd8_0 * 8 + s;
            *reinterpret_cast<unsigned short*>(&Vt[0][0] + d0 * 128 +
                (((l >> 3) ^ (d0 & 7)) << 4) + (l & 7) * 2) = u0[s];
            int d1 = vd8_1 * 8 + s;
            *reinterpret_cast<unsigned short*>(&Vt[0][0] + d1 * 128 +
                (((l >> 3) ^ (d1 & 7)) << 4) + (l & 7) * 2) = u1[s];
        }
    }
    __syncthreads();   // one full drain in prologue only

    int kcur = 0;      // t % 3
    int kst  = 2;      // (t+2) % 3

    for (int t = 0; t < nt; ++t) {
        const int vcur = t & 1;
        const bool preV = (t + 1 < nt);
        const bool preK = (t + 2 < nt);
        float4 vv0, vv1;
        if (preV) {   // V loads FIRST (so scatter's auto-wait leaves K flying)
            const size_t toff = (size_t)(t + 1) * 64 * DK_;
            vv0 = *reinterpret_cast<const float4*>(vb_ + toff + l * DK_ + vd8_0 * 8);
            vv1 = *reinterpret_cast<const float4*>(vb_ + toff + l * DK_ + vd8_1 * 8);
        }
        if (preK) {   // K(t+2) -> tri-buffer slot; stays in flight across barrier
            const size_t toff = (size_t)(t + 2) * 64 * DK_;
            #pragma unroll
            for (int it = 0; it < 2; ++it)
                gload_lds16(kb_ + toff + ksrc[it], &Ks[kst][0] + kdst[it]);
        }

        // ---- S^T = K . Q^T ----
        f32x4 s_acc[4] = {};
        __builtin_amdgcn_s_setprio(1);
        #pragma unroll
        for (int jf = 0; jf < 4; ++jf) {
            int row = jf * 16 + i16;
            bf16x8 ak0 = *reinterpret_cast<const bf16x8*>(
                &Ks[kcur][0] + row * 128 + ((g ^ (row & 7)) << 4));
            s_acc[jf] = __builtin_amdgcn_mfma_f32_16x16x32_bf16(
                ak0, qf0, s_acc[jf], 0, 0, 0);
            bf16x8 ak1 = *reinterpret_cast<const bf16x8*>(
                &Ks[kcur][0] + row * 128 + (((4 + g) ^ (row & 7)) << 4));
            s_acc[jf] = __builtin_amdgcn_mfma_f32_16x16x32_bf16(
                ak1, qf1, s_acc[jf], 0, 0, 0);
        }
        __builtin_amdgcn_s_setprio(0);

        // ---- causal mask (diagonal tile only) ----
        if (t == nt - 1) {
            #pragma unroll
            for (int jf = 0; jf < 4; ++jf)
                #pragma unroll
                for (int r = 0; r < 4; ++r)
                    if (t * 64 + jf * 16 + g * 4 + r > qrow)
                        s_acc[jf][r] = -1e30f;
        }

        // ---- lane-local max (15 fmax, NO shfl) ----
        float mx0 = fmaxf(fmaxf(s_acc[0][0], s_acc[0][1]),
                          fmaxf(s_acc[0][2], s_acc[0][3]));
        float mx1 = fmaxf(fmaxf(s_acc[1][0], s_acc[1][1]),
                          fmaxf(s_acc[1][2], s_acc[1][3]));
        float mx2 = fmaxf(fmaxf(s_acc[2][0], s_acc[2][1]),
                          fmaxf(s_acc[2][2], s_acc[2][3]));
        float mx3 = fmaxf(fmaxf(s_acc[3][0], s_acc[3][1]),
                          fmaxf(s_acc[3][2], s_acc[3][3]));
        float vmax = fmaxf(fmaxf(mx0, mx1), fmaxf(mx2, mx3));

        // ---- defer-max: lane-local ballot; reduce+rescale only if needed ----
        if (!__all(vmax <= m_run + 11.5f)) {
            float rmax = fmaxf(vmax, __shfl_xor(vmax, 16, 64));
            rmax = fmaxf(rmax, __shfl_xor(rmax, 32, 64));
            float m_new = fmaxf(m_run, rmax);
            float factor = __builtin_amdgcn_exp2f(m_run - m_new);
            m_run = m_new;
            l_run *= factor;
            #pragma unroll
            for (int df = 0; df < 4; ++df)
                #pragma unroll
                for (int r = 0; r < 4; ++r)
                    o[df][r] *= factor;
        }

        // ---- P = exp2(S - m), per-lane partial row-sum (NO shfl) ----
        float p[4][4];
        float psum = 0.0f;
        #pragma unroll
        for (int jf = 0; jf < 4; ++jf)
            #pragma unroll
            for (int r = 0; r < 4; ++r) {
                p[jf][r] = __builtin_amdgcn_exp2f(s_acc[jf][r] - m_run);
                psum += p[jf][r];
            }
        l_run += psum;

        // ---- pack P -> bf16, wave-local LDS (swizzled) ----
        #pragma unroll
        for (int jf = 0; jf < 4; ++jf)
            #pragma unroll
            for (int r0 = 0; r0 < 4; r0 += 2) {
                unsigned pk = pack2bf(p[jf][r0], p[jf][r0 + 1]);
                int jj = jf * 16 + g * 4 + r0;
                *reinterpret_cast<unsigned*>(pw + i16 * 128 +
                    ((jj * 2) ^ ((i16 & 7) << 4))) = pk;
            }

        // ---- O^T += V^T . P^T ----
        __builtin_amdgcn_s_setprio(1);
        #pragma unroll
        for (int jc = 0; jc < 2; ++jc) {
            bf16x8 bp = *reinterpret_cast<const bf16x8*>(pw + i16 * 128 +
                (((jc * 4 + g) ^ (i16 & 7)) << 4));
            #pragma unroll
            for (int df = 0; df < 4; ++df) {
                int row = df * 16 + i16;
                bf16x8 av = *reinterpret_cast<const bf16x8*>(
                    &Vt[vcur][0] + row * 128 +
                    (((jc * 4 + g) ^ (row & 7)) << 4));
                o[df] = __builtin_amdgcn_mfma_f32_16x16x32_bf16(
                    av, bp, o[df], 0, 0, 0);
            }
        }
        __builtin_amdgcn_s_setprio(0);

        if (preV) {  // scatter V(t+1); compiler waits only the V regs (vmcnt(2))
            unsigned char* vtb = &Vt[vcur ^ 1][0];
            const unsigned short* u0 = reinterpret_cast<const unsigned short*>(&vv0);
            const unsigned short* u1 = reinterpret_cast<const unsigned short*>(&vv1);
            #pragma unroll
            for (int s = 0; s < 8; ++s) {
                int d0 = vd8_0 * 8 + s;
                *reinterpret_cast<unsigned short*>(vtb + d0 * 128 +
                    (((l >> 3) ^ (d0 & 7)) << 4) + (l & 7) * 2) = u0[s];
                int d1 = vd8_1 * 8 + s;
                *reinterpret_cast<unsigned short*>(vtb + d1 * 128 +
                    (((l >> 3) ^ (d1 & 7)) << 4) + (l & 7) * 2) = u1[s];
            }
        }
        // counted-vmcnt tile barrier: K(t+2)'s 2 loads may stay in flight
        asm volatile("s_waitcnt vmcnt(2) lgkmcnt(0)\n\ts_barrier" ::: "memory");
        __builtin_amdgcn_sched_barrier(0);

        kcur = (kcur == 2) ? 0 : kcur + 1;
        kst  = (kst  == 2) ? 0 : kst  + 1;
    }

    // ---- epilogue: reduce per-lane l partials across row partners ----
    float l_tot = l_run;
    l_tot += __shfl_xor(l_tot, 16, 64);
    l_tot += __shfl_xor(l_tot, 32, 64);
    const float inv_l = 1.0f / l_tot;
    const int b_ = bh >> 4, h_ = bh & 15;
    __hip_bfloat16* orow = attn + ((size_t)b_ * S_ + qrow) * D_ + h_ * 64;
    #pragma unroll
    for (int df = 0; df < 4; ++df) {
        ushort4 uo = make_ushort4(
            bfbits(o[df][0] * inv_l), bfbits(o[df][1] * inv_l),
            bfbits(o[df][2] * inv_l), bfbits(o[df][3] * inv_l));
        *reinterpret_cast<ushort4*>(orow + df * 16 + g * 4) = uo;
    }
}

// ---------------------------------------------------------------------------
extern "C" void kernel_launch(void* const* d_in, const int* in_sizes, int n_in,
                              void* d_out, int out_size, void* d_ws, size_t ws_size,
                              hipStream_t stream) {
    const float* x       = (const float*)d_in[0];
    const float* w_q     = (const float*)d_in[1];
    const float* w_k     = (const float*)d_in[2];
    const float* w_v     = (const float*)d_in[3];
    const float* w_o     = (const float*)d_in[4];
    const float* sin_tab = (const float*)d_in[5];
    const float* cos_tab = (const float*)d_in[6];
    const int*   tpos    = (const int*)d_in[7];
    float* out = (float*)d_out;

    const size_t nM  = (size_t)B_ * S_ * D_;
    const size_t nW  = (size_t)D_ * D_;
    __hip_bfloat16* xb   = (__hip_bfloat16*)d_ws;
    __hip_bfloat16* wqb  = xb  + nM;
    __hip_bfloat16* wkb  = wqb + nW;
    __hip_bfloat16* wvb  = wkb + nW;
    __hip_bfloat16* wob  = wvb + nW;
    __hip_bfloat16* q_ws = wob + nW;
    __hip_bfloat16* k_ws = q_ws + nM;
    __hip_bfloat16* v_ws = k_ws + nM;
    __hip_bfloat16* a_ws = v_ws + nM;
    float2*         sct  = (float2*)(a_ws + nM);   // 65536 float2 = 512 KB

    to_bf16_kernel<<<dim3(1024, 9), 256, 0, stream>>>(
        x, w_q, w_k, w_v, w_o, sin_tab, cos_tab,
        xb, wqb, wkb, wvb, wob, sct);
    mfma_gemm_kernel<0><<<dim3(256, 1, 3), 256, 0, stream>>>(
        xb, wqb, wkb, wvb, q_ws, k_ws, v_ws, nullptr, sct, tpos);
    flash_mfma_kernel<<<1024, 256, 0, stream>>>(
        q_ws, k_ws, v_ws, a_ws);
    mfma_gemm_kernel<1><<<dim3(256, 1, 1), 256, 0, stream>>>(
        a_ws, wob, nullptr, nullptr, nullptr, nullptr, nullptr, out,
        sct, tpos);
}

// Round 13
// 132.954 us; speedup vs baseline: 1.0124x; 1.0124x over previous
//
#include <hip/hip_runtime.h>
#include <hip/hip_bf16.h>
#include <cstdint>

#define B_ 2
#define S_ 2048
#define D_ 1024
#define H_ 16
#define DK_ 64
#define HALF_ 32   // DK/2

typedef short bf16x8 __attribute__((ext_vector_type(8)));
typedef float f32x4  __attribute__((ext_vector_type(4)));
typedef unsigned int u32;

static __device__ __forceinline__ unsigned short bfbits(float f) {
    __hip_bfloat16 h = __float2bfloat16(f);
    unsigned short u; __builtin_memcpy(&u, &h, 2); return u;
}
static __device__ __forceinline__ float bf2f(unsigned short u) {
    unsigned v = (unsigned)u << 16; float f; __builtin_memcpy(&f, &v, 4); return f;
}
static __device__ __forceinline__ unsigned pack2bf(float a, float b) {
    return (unsigned)bfbits(a) | ((unsigned)bfbits(b) << 16);
}

// async 16B global->LDS (wave-uniform LDS base + lane*16; global addr per-lane)
static __device__ __forceinline__ void gload_lds16(const void* g, void* l) {
    __builtin_amdgcn_global_load_lds(
        (const __attribute__((address_space(1))) u32*)(uintptr_t)g,
        (__attribute__((address_space(3))) u32*)(uintptr_t)l,
        16, 0, 0);
}

// ---------------------------------------------------------------------------
// Kernel 0: fp32 -> bf16 conversion (x + 4 weights) and packed (cos,sin) table.
// ---------------------------------------------------------------------------
__global__ __launch_bounds__(256) void to_bf16_kernel(
    const float* __restrict__ x,
    const float* __restrict__ wq, const float* __restrict__ wk,
    const float* __restrict__ wv, const float* __restrict__ wo,
    const float* __restrict__ sin_tab, const float* __restrict__ cos_tab,
    __hip_bfloat16* __restrict__ xb,
    __hip_bfloat16* __restrict__ wqb, __hip_bfloat16* __restrict__ wkb,
    __hip_bfloat16* __restrict__ wvb, __hip_bfloat16* __restrict__ wob,
    float2* __restrict__ sctab)
{
    const int seg = blockIdx.y;   // 0..3 x quarters; 4..7 weights; 8 sincos
    if (seg == 8) {
        if (blockIdx.x >= 64) return;     // 65536 entries / 4 per thread
        size_t i = ((size_t)blockIdx.x * 256 + threadIdx.x) * 4;
        float4 c = *reinterpret_cast<const float4*>(cos_tab + i);
        float4 s = *reinterpret_cast<const float4*>(sin_tab + i);
        float4* dst = reinterpret_cast<float4*>(sctab + i);
        dst[0] = make_float4(c.x, s.x, c.y, s.y);
        dst[1] = make_float4(c.z, s.z, c.w, s.w);
        return;
    }
    const float* src;
    __hip_bfloat16* dst;
    size_t off = 0;
    if (seg < 4)       { src = x;  dst = xb;  off = (size_t)seg << 20; }
    else if (seg == 4) { src = wq; dst = wqb; }
    else if (seg == 5) { src = wk; dst = wkb; }
    else if (seg == 6) { src = wv; dst = wvb; }
    else               { src = wo; dst = wob; }
    size_t i = off + ((size_t)blockIdx.x * 256 + threadIdx.x) * 4;
    float4 v = *reinterpret_cast<const float4*>(src + i);
    ushort4 u = make_ushort4(bfbits(v.x), bfbits(v.y), bfbits(v.z), bfbits(v.w));
    *reinterpret_cast<ushort4*>(dst + i) = u;
}

// ---------------------------------------------------------------------------
// MFMA GEMM v2 (round-10 proven): C = A @ W^T, bf16 in, 16x16x32,
// 128x128 tile, BK=32, dbuf, XCD swizzle.
// MODE 0: QKV + RoPE epilogue; Q pre-scaled by 0.125*log2(e). MODE 1: out-proj.
// ---------------------------------------------------------------------------
template<int MODE>
__global__ __launch_bounds__(256) void mfma_gemm_kernel(
    const __hip_bfloat16* __restrict__ A,
    const __hip_bfloat16* __restrict__ Wq, const __hip_bfloat16* __restrict__ Wk,
    const __hip_bfloat16* __restrict__ Wv,
    __hip_bfloat16* __restrict__ out_q, __hip_bfloat16* __restrict__ out_k,
    __hip_bfloat16* __restrict__ out_v,
    float* __restrict__ out_f32,
    const float2* __restrict__ sctab,
    const int* __restrict__ tpos)
{
    constexpr int K = 1024;
    const int which = (MODE == 0) ? blockIdx.z : 3;
    const __hip_bfloat16* __restrict__ W =
        (MODE == 1) ? Wq : (which == 0 ? Wq : which == 1 ? Wk : Wv);

    __shared__ __align__(16) unsigned char As[2][128 * 4 * 16];  // 2 x 8 KB
    __shared__ __align__(16) unsigned char Bs[2][128 * 4 * 16];  // 2 x 8 KB

    const int tid = threadIdx.x;
    const int wid = tid >> 6;
    const int l   = tid & 63;
    const int g   = l >> 4;
    const int i16 = l & 15;
    const int wr  = wid >> 1, wc = wid & 1;

    const int wg   = blockIdx.x;
    const int tile = (wg & 7) * 32 + (wg >> 3);
    const int row0 = (tile >> 3) * 128;
    const int col0 = (tile & 7) * 128;

    const __hip_bfloat16* Abase = A + (size_t)row0 * K;
    const __hip_bfloat16* Wbase = W + (size_t)col0 * K;

    f32x4 acc[4][4];
    const f32x4 zero = {0.f, 0.f, 0.f, 0.f};
    #pragma unroll
    for (int mi = 0; mi < 4; ++mi)
        #pragma unroll
        for (int ni = 0; ni < 4; ++ni) acc[mi][ni] = zero;

    int a_off[4], b_off[4];
    #pragma unroll
    for (int f = 0; f < 4; ++f) {
        int ra = wr * 64 + f * 16 + i16;
        a_off[f] = (ra * 4 + (g ^ ((ra >> 1) & 3))) * 16;
        int rb = wc * 64 + f * 16 + i16;
        b_off[f] = (rb * 4 + (g ^ ((rb >> 1) & 3))) * 16;
    }

    int st_goff[2], st_loff[2];
    #pragma unroll
    for (int it = 0; it < 2; ++it) {
        int c = it * 256 + wid * 64 + l;
        int row = c >> 2;
        int kc = (c & 3) ^ ((row >> 1) & 3);
        st_goff[it] = row * K + kc * 8;
        st_loff[it] = (it * 256 + wid * 64) * 16;
    }

    #pragma unroll
    for (int it = 0; it < 2; ++it) {
        gload_lds16(Abase + st_goff[it], &As[0][0] + st_loff[it]);
        gload_lds16(Wbase + st_goff[it], &Bs[0][0] + st_loff[it]);
    }
    __syncthreads();

    for (int t = 0; t < K / 32; ++t) {
        const int cur = t & 1;
        if (t + 1 < K / 32) {
            const int k1 = (t + 1) * 32;
            #pragma unroll
            for (int it = 0; it < 2; ++it) {
                gload_lds16(Abase + k1 + st_goff[it], &As[cur ^ 1][0] + st_loff[it]);
                gload_lds16(Wbase + k1 + st_goff[it], &Bs[cur ^ 1][0] + st_loff[it]);
            }
        }
        bf16x8 af[4], bfr[4];
        #pragma unroll
        for (int f = 0; f < 4; ++f) {
            af[f]  = *reinterpret_cast<const bf16x8*>(&As[cur][0] + a_off[f]);
            bfr[f] = *reinterpret_cast<const bf16x8*>(&Bs[cur][0] + b_off[f]);
        }
        #pragma unroll
        for (int mi = 0; mi < 4; ++mi)
            #pragma unroll
            for (int ni = 0; ni < 4; ++ni)
                acc[mi][ni] = __builtin_amdgcn_mfma_f32_16x16x32_bf16(
                    af[mi], bfr[ni], acc[mi][ni], 0, 0, 0);
        __syncthreads();
    }

    if (MODE == 0) {
        __hip_bfloat16* __restrict__ outp =
            which == 0 ? out_q : which == 1 ? out_k : out_v;
        const int head = (col0 >> 6) + wc;
        #pragma unroll
        for (int mi = 0; mi < 4; ++mi) {
            #pragma unroll
            for (int r = 0; r < 4; ++r) {
                const int gi = row0 + wr * 64 + mi * 16 + g * 4 + r;
                const int b_ = gi >> 11;
                const int s_ = gi & (S_ - 1);
                const int pos = tpos[gi];
                const float2* sc = sctab + pos * HALF_;
                __hip_bfloat16* orow =
                    outp + (((size_t)b_ * H_ + head) * S_ + s_) * DK_;
                #pragma unroll
                for (int ni = 0; ni < 4; ++ni) {
                    float val = acc[mi][ni][r];
                    float other = __shfl_xor(val, 1, 64);
                    const int dk = ni * 16 + i16;
                    float res;
                    if (which < 2) {
                        float2 cs = sc[ni * 8 + (i16 >> 1)];
                        res = (i16 & 1) ? fmaf(cs.y, other, cs.x * val)
                                        : (cs.x * val - cs.y * other);
                    } else {
                        res = val;
                    }
                    // 0.125 * log2(e): softmax runs in exp2 domain
                    if (which == 0) res *= 0.180336880f;
                    orow[dk] = __float2bfloat16(res);
                }
            }
        }
    } else {
        #pragma unroll
        for (int mi = 0; mi < 4; ++mi) {
            #pragma unroll
            for (int r = 0; r < 4; ++r) {
                const int gi = row0 + wr * 64 + mi * 16 + g * 4 + r;
                float* orow = out_f32 + (size_t)gi * D_ + col0 + wc * 64;
                #pragma unroll
                for (int ni = 0; ni < 4; ++ni)
                    orow[ni * 16 + i16] = acc[mi][ni][r];
            }
        }
    }
}

// ---------------------------------------------------------------------------
// Kernel 2 (v9): causal flash attention = round-10 structure (QBLK=64,
// 4 waves, dbuf K/V^T, conflict-free V scatter, shfl-free steady state,
// deferred l-reduction) + SPLIT-K for uniform backfillable blocks:
//   - qsb < 16: one block, tiles [0, qsb+1)           (1..16 tiles)
//   - qsb >= 16: two blocks, tiles [0,h) / [h,qsb+1)  (8..16 tiles each)
//   grid = 32 bh x 48 items = 1536 blocks (6/CU queued, 4 resident+backfill)
// Split parts write unnormalized O (bf16) + per-row (m,l) (fp32) to ws;
// merge_kernel combines. Inner loop byte-identical to round 10.
// ---------------------------------------------------------------------------
__global__ __launch_bounds__(256) void flash_mfma_kernel(
    const __hip_bfloat16* __restrict__ q,   // (b,h,s,dk), pre-scaled
    const __hip_bfloat16* __restrict__ k,
    const __hip_bfloat16* __restrict__ v,
    __hip_bfloat16* __restrict__ attn,      // (b,s,D) bf16
    __hip_bfloat16* __restrict__ opart,     // [1024][64][64] bf16
    float2* __restrict__ mlpart)            // [1024][64] (m,l)
{
    __shared__ __align__(16) unsigned char Ks[2][64 * 128];  // 16 KB
    __shared__ __align__(16) unsigned char Vt[2][64 * 128];  // 16 KB
    __shared__ __align__(16) unsigned char Ps[4][16 * 128];  //  8 KB

    const int tid = threadIdx.x;
    const int w   = tid >> 6;        // 0..3
    const int l   = tid & 63;
    const int g   = l >> 4;
    const int i16 = l & 15;

    // item decode: xcd-local bh; j = work item 0..47 (longest first-ish)
    const int wgid = blockIdx.x;              // 0..1535
    const int xcd  = wgid & 7;
    const int idx  = wgid >> 3;               // 0..191
    const int bh   = xcd * 4 + (idx & 3);
    const int j    = idx >> 2;                // 0..47
    int qsb, t0, t1, part;
    bool split;
    if (j < 32) {                 // split halves of qsb 31..16
        split = true;
        qsb  = 31 - (j >> 1);
        part = j & 1;
        int h = (qsb + 1) >> 1;
        t0 = part ? h : 0;
        t1 = part ? (qsb + 1) : h;
    } else {                      // unsplit qsb 15..0
        split = false;
        qsb  = 47 - j;
        part = 0;
        t0 = 0;
        t1 = qsb + 1;
    }

    const size_t base = (size_t)bh * S_ * DK_;
    const __hip_bfloat16* kb_ = k + base;
    const __hip_bfloat16* vb_ = v + base;

    // K staging geometry: 512 chunks of 16B, 2 per thread (linear LDS dest,
    // inverse swizzle folded into global source)
    int ksrc[2], kdst[2];
    #pragma unroll
    for (int it = 0; it < 2; ++it) {
        int c = it * 256 + tid;
        int krow = c >> 3;
        int kchunk = (c & 7) ^ (krow & 7);
        ksrc[it] = krow * DK_ + kchunk * 8;
        kdst[it] = c * 16;
    }
    // V staging: per-lane row j=l, wave-constant d8 (conflict-free, 2-way)
    const int vd8_0 = w;        // it = 0
    const int vd8_1 = 4 + w;    // it = 1
    unsigned char* const pw = &Ps[w][0];

    const int qrow = qsb * 64 + w * 16 + i16;  // this lane's q-row

    // Q fragments in registers
    bf16x8 qf0, qf1;
    {
        const __hip_bfloat16* qp = q + base + (size_t)qrow * DK_ + g * 8;
        qf0 = *reinterpret_cast<const bf16x8*>(qp);
        qf1 = *reinterpret_cast<const bf16x8*>(qp + 32);
    }

    f32x4 o[4] = {};
    float m_run = -1e30f, l_run = 0.0f;   // l_run = per-lane partial

    // prologue: stage tile t0 into buffer 0
    {
        const size_t toff = (size_t)t0 * 64 * DK_;
        #pragma unroll
        for (int it = 0; it < 2; ++it)
            gload_lds16(kb_ + toff + ksrc[it], &Ks[0][0] + kdst[it]);
        float4 vv0 = *reinterpret_cast<const float4*>(vb_ + toff + l * DK_ + vd8_0 * 8);
        float4 vv1 = *reinterpret_cast<const float4*>(vb_ + toff + l * DK_ + vd8_1 * 8);
        const unsigned short* u0 = reinterpret_cast<const unsigned short*>(&vv0);
        const unsigned short* u1 = reinterpret_cast<const unsigned short*>(&vv1);
        #pragma unroll
        for (int s = 0; s < 8; ++s) {
            int d0 = vd8_0 * 8 + s;
            *reinterpret_cast<unsigned short*>(&Vt[0][0] + d0 * 128 +
                (((l >> 3) ^ (d0 & 7)) << 4) + (l & 7) * 2) = u0[s];
            int d1 = vd8_1 * 8 + s;
            *reinterpret_cast<unsigned short*>(&Vt[0][0] + d1 * 128 +
                (((l >> 3) ^ (d1 & 7)) << 4) + (l & 7) * 2) = u1[s];
        }
    }
    __syncthreads();

    for (int t = t0; t < t1; ++t) {
        const int cur = (t - t0) & 1;
        const bool pre = (t + 1 < t1);
        float4 vv0, vv1;
        if (pre) {   // issue next-tile loads early (hide under compute)
            const size_t toff = (size_t)(t + 1) * 64 * DK_;
            #pragma unroll
            for (int it = 0; it < 2; ++it)
                gload_lds16(kb_ + toff + ksrc[it], &Ks[cur ^ 1][0] + kdst[it]);
            vv0 = *reinterpret_cast<const float4*>(vb_ + toff + l * DK_ + vd8_0 * 8);
            vv1 = *reinterpret_cast<const float4*>(vb_ + toff + l * DK_ + vd8_1 * 8);
        }

        // ---- S^T = K . Q^T ----
        f32x4 s_acc[4] = {};
        __builtin_amdgcn_s_setprio(1);
        #pragma unroll
        for (int jf = 0; jf < 4; ++jf) {
            int row = jf * 16 + i16;
            bf16x8 ak0 = *reinterpret_cast<const bf16x8*>(
                &Ks[cur][0] + row * 128 + ((g ^ (row & 7)) << 4));
            s_acc[jf] = __builtin_amdgcn_mfma_f32_16x16x32_bf16(
                ak0, qf0, s_acc[jf], 0, 0, 0);
            bf16x8 ak1 = *reinterpret_cast<const bf16x8*>(
                &Ks[cur][0] + row * 128 + (((4 + g) ^ (row & 7)) << 4));
            s_acc[jf] = __builtin_amdgcn_mfma_f32_16x16x32_bf16(
                ak1, qf1, s_acc[jf], 0, 0, 0);
        }
        __builtin_amdgcn_s_setprio(0);

        // ---- causal mask (diagonal tile only; always in the last part) ----
        if (t == qsb) {
            #pragma unroll
            for (int jf = 0; jf < 4; ++jf)
                #pragma unroll
                for (int r = 0; r < 4; ++r)
                    if (t * 64 + jf * 16 + g * 4 + r > qrow)
                        s_acc[jf][r] = -1e30f;
        }

        // ---- lane-local max (15 fmax, NO shfl) ----
        float mx0 = fmaxf(fmaxf(s_acc[0][0], s_acc[0][1]),
                          fmaxf(s_acc[0][2], s_acc[0][3]));
        float mx1 = fmaxf(fmaxf(s_acc[1][0], s_acc[1][1]),
                          fmaxf(s_acc[1][2], s_acc[1][3]));
        float mx2 = fmaxf(fmaxf(s_acc[2][0], s_acc[2][1]),
                          fmaxf(s_acc[2][2], s_acc[2][3]));
        float mx3 = fmaxf(fmaxf(s_acc[3][0], s_acc[3][1]),
                          fmaxf(s_acc[3][2], s_acc[3][3]));
        float vmax = fmaxf(fmaxf(mx0, mx1), fmaxf(mx2, mx3));

        // ---- defer-max: lane-local ballot; reduce+rescale only if needed ----
        if (!__all(vmax <= m_run + 11.5f)) {
            float rmax = fmaxf(vmax, __shfl_xor(vmax, 16, 64));
            rmax = fmaxf(rmax, __shfl_xor(rmax, 32, 64));
            float m_new = fmaxf(m_run, rmax);
            float factor = __builtin_amdgcn_exp2f(m_run - m_new);
            m_run = m_new;
            l_run *= factor;
            #pragma unroll
            for (int df = 0; df < 4; ++df)
                #pragma unroll
                for (int r = 0; r < 4; ++r)
                    o[df][r] *= factor;
        }

        // ---- P = exp2(S - m), per-lane partial row-sum (NO shfl) ----
        float p[4][4];
        float psum = 0.0f;
        #pragma unroll
        for (int jf = 0; jf < 4; ++jf)
            #pragma unroll
            for (int r = 0; r < 4; ++r) {
                p[jf][r] = __builtin_amdgcn_exp2f(s_acc[jf][r] - m_run);
                psum += p[jf][r];
            }
        l_run += psum;

        // ---- pack P -> bf16, wave-local LDS (swizzled) ----
        #pragma unroll
        for (int jf = 0; jf < 4; ++jf)
            #pragma unroll
            for (int r0 = 0; r0 < 4; r0 += 2) {
                unsigned pk = pack2bf(p[jf][r0], p[jf][r0 + 1]);
                int jj = jf * 16 + g * 4 + r0;
                *reinterpret_cast<unsigned*>(pw + i16 * 128 +
                    ((jj * 2) ^ ((i16 & 7) << 4))) = pk;
            }

        // ---- O^T += V^T . P^T ----
        __builtin_amdgcn_s_setprio(1);
        #pragma unroll
        for (int jc = 0; jc < 2; ++jc) {
            bf16x8 bp = *reinterpret_cast<const bf16x8*>(pw + i16 * 128 +
                (((jc * 4 + g) ^ (i16 & 7)) << 4));
            #pragma unroll
            for (int df = 0; df < 4; ++df) {
                int row = df * 16 + i16;
                bf16x8 av = *reinterpret_cast<const bf16x8*>(
                    &Vt[cur][0] + row * 128 +
                    (((jc * 4 + g) ^ (row & 7)) << 4));
                o[df] = __builtin_amdgcn_mfma_f32_16x16x32_bf16(
                    av, bp, o[df], 0, 0, 0);
            }
        }
        __builtin_amdgcn_s_setprio(0);

        if (pre) {   // scatter-write next V^T after compute (conflict-free)
            unsigned char* vtb = &Vt[cur ^ 1][0];
            const unsigned short* u0 = reinterpret_cast<const unsigned short*>(&vv0);
            const unsigned short* u1 = reinterpret_cast<const unsigned short*>(&vv1);
            #pragma unroll
            for (int s = 0; s < 8; ++s) {
                int d0 = vd8_0 * 8 + s;
                *reinterpret_cast<unsigned short*>(vtb + d0 * 128 +
                    (((l >> 3) ^ (d0 & 7)) << 4) + (l & 7) * 2) = u0[s];
                int d1 = vd8_1 * 8 + s;
                *reinterpret_cast<unsigned short*>(vtb + d1 * 128 +
                    (((l >> 3) ^ (d1 & 7)) << 4) + (l & 7) * 2) = u1[s];
            }
        }
        __syncthreads();   // drains gload_lds (vmcnt) + LDS writes
    }

    // ---- epilogue: reduce per-lane l partials across row partners ----
    float l_tot = l_run;
    l_tot += __shfl_xor(l_tot, 16, 64);
    l_tot += __shfl_xor(l_tot, 32, 64);

    if (!split) {
        const float inv_l = 1.0f / l_tot;
        const int b_ = bh >> 4, h_ = bh & 15;
        __hip_bfloat16* orow = attn + ((size_t)b_ * S_ + qrow) * D_ + h_ * 64;
        #pragma unroll
        for (int df = 0; df < 4; ++df) {
            ushort4 uo = make_ushort4(
                bfbits(o[df][0] * inv_l), bfbits(o[df][1] * inv_l),
                bfbits(o[df][2] * inv_l), bfbits(o[df][3] * inv_l));
            *reinterpret_cast<ushort4*>(orow + df * 16 + g * 4) = uo;
        }
    } else {
        // partial store: unnormalized O (bf16) + (m, l) once per row
        const int p_ = (bh * 16 + (qsb - 16)) * 2 + part;
        const int rloc = w * 16 + i16;
        if (g == 0) mlpart[p_ * 64 + rloc] = make_float2(m_run, l_tot);
        __hip_bfloat16* orow = opart + ((size_t)p_ * 64 + rloc) * 64;
        #pragma unroll
        for (int df = 0; df < 4; ++df) {
            ushort4 uo = make_ushort4(
                bfbits(o[df][0]), bfbits(o[df][1]),
                bfbits(o[df][2]), bfbits(o[df][3]));
            *reinterpret_cast<ushort4*>(orow + df * 16 + g * 4) = uo;
        }
    }
}

// ---------------------------------------------------------------------------
// Kernel 2b: merge split-K partials -> attn rows for qsb >= 16.
// 32768 rows x 64 dk; thread = (row, 4 dk). out = (f0*O0 + f1*O1)/(f0*l0+f1*l1)
// with f_i = 2^(m_i - max(m0,m1)).
// ---------------------------------------------------------------------------
__global__ __launch_bounds__(256) void merge_kernel(
    const __hip_bfloat16* __restrict__ opart,
    const float2* __restrict__ mlpart,
    __hip_bfloat16* __restrict__ attn)
{
    const int u = blockIdx.x * 256 + threadIdx.x;   // 0..524287
    const int row = u >> 4;                          // 0..32767
    const int dk0 = (u & 15) * 4;
    const int bh = row >> 10;
    const int rem = row & 1023;
    const int qsb16 = rem >> 6;
    const int r64 = rem & 63;
    const int p0 = (bh * 16 + qsb16) * 2;

    float2 ml0 = mlpart[p0 * 64 + r64];
    float2 ml1 = mlpart[(p0 + 1) * 64 + r64];
    float mstar = fmaxf(ml0.x, ml1.x);
    float f0 = __builtin_amdgcn_exp2f(ml0.x - mstar);
    float f1 = __builtin_amdgcn_exp2f(ml1.x - mstar);
    float inv = 1.0f / (f0 * ml0.y + f1 * ml1.y);

    ushort4 u0 = *reinterpret_cast<const ushort4*>(
        opart + ((size_t)p0 * 64 + r64) * 64 + dk0);
    ushort4 u1 = *reinterpret_cast<const ushort4*>(
        opart + ((size_t)(p0 + 1) * 64 + r64) * 64 + dk0);

    ushort4 res = make_ushort4(
        bfbits((f0 * bf2f(u0.x) + f1 * bf2f(u1.x)) * inv),
        bfbits((f0 * bf2f(u0.y) + f1 * bf2f(u1.y)) * inv),
        bfbits((f0 * bf2f(u0.z) + f1 * bf2f(u1.z)) * inv),
        bfbits((f0 * bf2f(u0.w) + f1 * bf2f(u1.w)) * inv));

    const int qsb = 16 + qsb16;
    const int s_ = qsb * 64 + r64;
    const int b_ = bh >> 4, h_ = bh & 15;
    *reinterpret_cast<ushort4*>(
        attn + ((size_t)b_ * S_ + s_) * D_ + h_ * 64 + dk0) = res;
}

// ---------------------------------------------------------------------------
extern "C" void kernel_launch(void* const* d_in, const int* in_sizes, int n_in,
                              void* d_out, int out_size, void* d_ws, size_t ws_size,
                              hipStream_t stream) {
    const float* x       = (const float*)d_in[0];
    const float* w_q     = (const float*)d_in[1];
    const float* w_k     = (const float*)d_in[2];
    const float* w_v     = (const float*)d_in[3];
    const float* w_o     = (const float*)d_in[4];
    const float* sin_tab = (const float*)d_in[5];
    const float* cos_tab = (const float*)d_in[6];
    const int*   tpos    = (const int*)d_in[7];
    float* out = (float*)d_out;

    const size_t nM  = (size_t)B_ * S_ * D_;
    const size_t nW  = (size_t)D_ * D_;
    __hip_bfloat16* xb   = (__hip_bfloat16*)d_ws;
    __hip_bfloat16* wqb  = xb  + nM;
    __hip_bfloat16* wkb  = wqb + nW;
    __hip_bfloat16* wvb  = wkb + nW;
    __hip_bfloat16* wob  = wvb + nW;
    __hip_bfloat16* q_ws = wob + nW;
    __hip_bfloat16* k_ws = q_ws + nM;
    __hip_bfloat16* v_ws = k_ws + nM;
    __hip_bfloat16* a_ws = v_ws + nM;
    float2*         sct  = (float2*)(a_ws + nM);        // 512 KB
    __hip_bfloat16* opart = (__hip_bfloat16*)(sct + 65536);  // 8 MB
    float2*         mlp   = (float2*)(opart + (size_t)1024 * 64 * 64);  // 512 KB

    to_bf16_kernel<<<dim3(1024, 9), 256, 0, stream>>>(
        x, w_q, w_k, w_v, w_o, sin_tab, cos_tab,
        xb, wqb, wkb, wvb, wob, sct);
    mfma_gemm_kernel<0><<<dim3(256, 1, 3), 256, 0, stream>>>(
        xb, wqb, wkb, wvb, q_ws, k_ws, v_ws, nullptr, sct, tpos);
    flash_mfma_kernel<<<1536, 256, 0, stream>>>(
        q_ws, k_ws, v_ws, a_ws, opart, mlp);
    merge_kernel<<<2048, 256, 0, stream>>>(opart, mlp, a_ws);
    mfma_gemm_kernel<1><<<dim3(256, 1, 1), 256, 0, stream>>>(
        a_ws, wob, nullptr, nullptr, nullptr, nullptr, nullptr, out,
        sct, tpos);
}

// Round 14
// 120.305 us; speedup vs baseline: 1.1188x; 1.1051x over previous
//
#include <hip/hip_runtime.h>
#include <hip/hip_bf16.h>
#include <cstdint>

#define B_ 2
#define S_ 2048
#define D_ 1024
#define H_ 16
#define DK_ 64
#define HALF_ 32   // DK/2

typedef short bf16x8 __attribute__((ext_vector_type(8)));
typedef float f32x4  __attribute__((ext_vector_type(4)));
typedef unsigned int u32;

static __device__ __forceinline__ unsigned short bfbits(float f) {
    __hip_bfloat16 h = __float2bfloat16(f);
    unsigned short u; __builtin_memcpy(&u, &h, 2); return u;
}
static __device__ __forceinline__ unsigned pack2bf(float a, float b) {
    return (unsigned)bfbits(a) | ((unsigned)bfbits(b) << 16);
}

// async 16B global->LDS (wave-uniform LDS base + lane*16; global addr per-lane)
static __device__ __forceinline__ void gload_lds16(const void* g, void* l) {
    __builtin_amdgcn_global_load_lds(
        (const __attribute__((address_space(1))) u32*)(uintptr_t)g,
        (__attribute__((address_space(3))) u32*)(uintptr_t)l,
        16, 0, 0);
}

// ---------------------------------------------------------------------------
// Kernel 0: fp32 -> bf16 conversion (x + 4 weights) and packed (cos,sin) table.
// ---------------------------------------------------------------------------
__global__ __launch_bounds__(256) void to_bf16_kernel(
    const float* __restrict__ x,
    const float* __restrict__ wq, const float* __restrict__ wk,
    const float* __restrict__ wv, const float* __restrict__ wo,
    const float* __restrict__ sin_tab, const float* __restrict__ cos_tab,
    __hip_bfloat16* __restrict__ xb,
    __hip_bfloat16* __restrict__ wqb, __hip_bfloat16* __restrict__ wkb,
    __hip_bfloat16* __restrict__ wvb, __hip_bfloat16* __restrict__ wob,
    float2* __restrict__ sctab)
{
    const int seg = blockIdx.y;   // 0..3 x quarters; 4..7 weights; 8 sincos
    if (seg == 8) {
        if (blockIdx.x >= 64) return;     // 65536 entries / 4 per thread
        size_t i = ((size_t)blockIdx.x * 256 + threadIdx.x) * 4;
        float4 c = *reinterpret_cast<const float4*>(cos_tab + i);
        float4 s = *reinterpret_cast<const float4*>(sin_tab + i);
        float4* dst = reinterpret_cast<float4*>(sctab + i);
        dst[0] = make_float4(c.x, s.x, c.y, s.y);
        dst[1] = make_float4(c.z, s.z, c.w, s.w);
        return;
    }
    const float* src;
    __hip_bfloat16* dst;
    size_t off = 0;
    if (seg < 4)       { src = x;  dst = xb;  off = (size_t)seg << 20; }
    else if (seg == 4) { src = wq; dst = wqb; }
    else if (seg == 5) { src = wk; dst = wkb; }
    else if (seg == 6) { src = wv; dst = wvb; }
    else               { src = wo; dst = wob; }
    size_t i = off + ((size_t)blockIdx.x * 256 + threadIdx.x) * 4;
    float4 v = *reinterpret_cast<const float4*>(src + i);
    ushort4 u = make_ushort4(bfbits(v.x), bfbits(v.y), bfbits(v.z), bfbits(v.w));
    *reinterpret_cast<ushort4*>(dst + i) = u;
}

// ---------------------------------------------------------------------------
// MFMA GEMM v2 (round-10 proven): C = A @ W^T, bf16 in, 16x16x32,
// 128x128 tile, BK=32, dbuf, XCD swizzle.
// MODE 0: QKV + RoPE epilogue; Q pre-scaled by 0.125*log2(e). MODE 1: out-proj.
// ---------------------------------------------------------------------------
template<int MODE>
__global__ __launch_bounds__(256) void mfma_gemm_kernel(
    const __hip_bfloat16* __restrict__ A,
    const __hip_bfloat16* __restrict__ Wq, const __hip_bfloat16* __restrict__ Wk,
    const __hip_bfloat16* __restrict__ Wv,
    __hip_bfloat16* __restrict__ out_q, __hip_bfloat16* __restrict__ out_k,
    __hip_bfloat16* __restrict__ out_v,
    float* __restrict__ out_f32,
    const float2* __restrict__ sctab,
    const int* __restrict__ tpos)
{
    constexpr int K = 1024;
    const int which = (MODE == 0) ? blockIdx.z : 3;
    const __hip_bfloat16* __restrict__ W =
        (MODE == 1) ? Wq : (which == 0 ? Wq : which == 1 ? Wk : Wv);

    __shared__ __align__(16) unsigned char As[2][128 * 4 * 16];  // 2 x 8 KB
    __shared__ __align__(16) unsigned char Bs[2][128 * 4 * 16];  // 2 x 8 KB

    const int tid = threadIdx.x;
    const int wid = tid >> 6;
    const int l   = tid & 63;
    const int g   = l >> 4;
    const int i16 = l & 15;
    const int wr  = wid >> 1, wc = wid & 1;

    const int wg   = blockIdx.x;
    const int tile = (wg & 7) * 32 + (wg >> 3);
    const int row0 = (tile >> 3) * 128;
    const int col0 = (tile & 7) * 128;

    const __hip_bfloat16* Abase = A + (size_t)row0 * K;
    const __hip_bfloat16* Wbase = W + (size_t)col0 * K;

    f32x4 acc[4][4];
    const f32x4 zero = {0.f, 0.f, 0.f, 0.f};
    #pragma unroll
    for (int mi = 0; mi < 4; ++mi)
        #pragma unroll
        for (int ni = 0; ni < 4; ++ni) acc[mi][ni] = zero;

    int a_off[4], b_off[4];
    #pragma unroll
    for (int f = 0; f < 4; ++f) {
        int ra = wr * 64 + f * 16 + i16;
        a_off[f] = (ra * 4 + (g ^ ((ra >> 1) & 3))) * 16;
        int rb = wc * 64 + f * 16 + i16;
        b_off[f] = (rb * 4 + (g ^ ((rb >> 1) & 3))) * 16;
    }

    int st_goff[2], st_loff[2];
    #pragma unroll
    for (int it = 0; it < 2; ++it) {
        int c = it * 256 + wid * 64 + l;
        int row = c >> 2;
        int kc = (c & 3) ^ ((row >> 1) & 3);
        st_goff[it] = row * K + kc * 8;
        st_loff[it] = (it * 256 + wid * 64) * 16;
    }

    #pragma unroll
    for (int it = 0; it < 2; ++it) {
        gload_lds16(Abase + st_goff[it], &As[0][0] + st_loff[it]);
        gload_lds16(Wbase + st_goff[it], &Bs[0][0] + st_loff[it]);
    }
    __syncthreads();

    for (int t = 0; t < K / 32; ++t) {
        const int cur = t & 1;
        if (t + 1 < K / 32) {
            const int k1 = (t + 1) * 32;
            #pragma unroll
            for (int it = 0; it < 2; ++it) {
                gload_lds16(Abase + k1 + st_goff[it], &As[cur ^ 1][0] + st_loff[it]);
                gload_lds16(Wbase + k1 + st_goff[it], &Bs[cur ^ 1][0] + st_loff[it]);
            }
        }
        bf16x8 af[4], bfr[4];
        #pragma unroll
        for (int f = 0; f < 4; ++f) {
            af[f]  = *reinterpret_cast<const bf16x8*>(&As[cur][0] + a_off[f]);
            bfr[f] = *reinterpret_cast<const bf16x8*>(&Bs[cur][0] + b_off[f]);
        }
        #pragma unroll
        for (int mi = 0; mi < 4; ++mi)
            #pragma unroll
            for (int ni = 0; ni < 4; ++ni)
                acc[mi][ni] = __builtin_amdgcn_mfma_f32_16x16x32_bf16(
                    af[mi], bfr[ni], acc[mi][ni], 0, 0, 0);
        __syncthreads();
    }

    if (MODE == 0) {
        __hip_bfloat16* __restrict__ outp =
            which == 0 ? out_q : which == 1 ? out_k : out_v;
        const int head = (col0 >> 6) + wc;
        #pragma unroll
        for (int mi = 0; mi < 4; ++mi) {
            #pragma unroll
            for (int r = 0; r < 4; ++r) {
                const int gi = row0 + wr * 64 + mi * 16 + g * 4 + r;
                const int b_ = gi >> 11;
                const int s_ = gi & (S_ - 1);
                const int pos = tpos[gi];
                const float2* sc = sctab + pos * HALF_;
                __hip_bfloat16* orow =
                    outp + (((size_t)b_ * H_ + head) * S_ + s_) * DK_;
                #pragma unroll
                for (int ni = 0; ni < 4; ++ni) {
                    float val = acc[mi][ni][r];
                    const int dk = ni * 16 + i16;
                    float res;
                    if (which < 2) {   // block-uniform: V-blocks skip the shfl
                        float other = __shfl_xor(val, 1, 64);
                        float2 cs = sc[ni * 8 + (i16 >> 1)];
                        res = (i16 & 1) ? fmaf(cs.y, other, cs.x * val)
                                        : (cs.x * val - cs.y * other);
                    } else {
                        res = val;
                    }
                    // 0.125 * log2(e): softmax runs in exp2 domain
                    if (which == 0) res *= 0.180336880f;
                    orow[dk] = __float2bfloat16(res);
                }
            }
        }
    } else {
        #pragma unroll
        for (int mi = 0; mi < 4; ++mi) {
            #pragma unroll
            for (int r = 0; r < 4; ++r) {
                const int gi = row0 + wr * 64 + mi * 16 + g * 4 + r;
                float* orow = out_f32 + (size_t)gi * D_ + col0 + wc * 64;
                #pragma unroll
                for (int ni = 0; ni < 4; ++ni)
                    orow[ni * 16 + i16] = acc[mi][ni][r];
            }
        }
    }
}

// ---------------------------------------------------------------------------
// Kernel 2 (v7 = round-10 proven optimum): causal flash attention.
//  QBLK=64, 4 waves, 1024 blocks, balanced per-CU mapping (each CU's 4
//  blocks total exactly 66 tiles), dbuf K (gload_lds) + V^T (conflict-free
//  reg scatter), shfl-free steady state (lane-local defer-max ballot),
//  deferred l-reduction. Round-14 tweak: psum accumulated as an explicit
//  depth-4 tree (compiler cannot reassociate fp) — shortens the per-tile
//  softmax dependent chain by ~48 cycles.
// ---------------------------------------------------------------------------
__global__ __launch_bounds__(256) void flash_mfma_kernel(
    const __hip_bfloat16* __restrict__ q,   // (b,h,s,dk), pre-scaled
    const __hip_bfloat16* __restrict__ k,
    const __hip_bfloat16* __restrict__ v,
    __hip_bfloat16* __restrict__ attn)      // (b,s,D) bf16
{
    __shared__ __align__(16) unsigned char Ks[2][64 * 128];  // 16 KB
    __shared__ __align__(16) unsigned char Vt[2][64 * 128];  // 16 KB
    __shared__ __align__(16) unsigned char Ps[4][16 * 128];  //  8 KB

    const int tid = threadIdx.x;
    const int w   = tid >> 6;        // 0..3
    const int l   = tid & 63;
    const int g   = l >> 4;
    const int i16 = l & 15;

    // balanced block swizzle: per-XCD bh locality; each CU's 4 blocks
    // (idx = r*32 + c, r=0..3) get qsb = {31-c, c, 31-c, c} -> 66 tiles total
    const int wgid = blockIdx.x;              // 0..1023
    const int xcd  = wgid & 7;
    const int idx  = wgid >> 3;               // 0..127
    const int r_   = idx >> 5;                // 0..3
    const int c_   = idx & 31;                // 0..31
    const int bh   = xcd * 4 + r_;
    const int qsb  = (r_ & 1) ? c_ : (31 - c_);

    const size_t base = (size_t)bh * S_ * DK_;
    const __hip_bfloat16* kb_ = k + base;
    const __hip_bfloat16* vb_ = v + base;
    const int nt = qsb + 1;

    // K staging geometry: 512 chunks of 16B, 2 per thread (linear LDS dest,
    // inverse swizzle folded into global source)
    int ksrc[2], kdst[2];
    #pragma unroll
    for (int it = 0; it < 2; ++it) {
        int c = it * 256 + tid;
        int krow = c >> 3;
        int kchunk = (c & 7) ^ (krow & 7);
        ksrc[it] = krow * DK_ + kchunk * 8;
        kdst[it] = c * 16;
    }
    // V staging: per-lane row j=l, wave-constant d8 (conflict-free, 2-way)
    const int vd8_0 = w;        // it = 0
    const int vd8_1 = 4 + w;    // it = 1
    unsigned char* const pw = &Ps[w][0];

    const int qrow = qsb * 64 + w * 16 + i16;  // this lane's q-row

    // Q fragments in registers
    bf16x8 qf0, qf1;
    {
        const __hip_bfloat16* qp = q + base + (size_t)qrow * DK_ + g * 8;
        qf0 = *reinterpret_cast<const bf16x8*>(qp);
        qf1 = *reinterpret_cast<const bf16x8*>(qp + 32);
    }

    f32x4 o[4] = {};
    float m_run = -1e30f, l_run = 0.0f;   // l_run = per-lane partial

    // prologue: stage tile 0 into buffer 0
    #pragma unroll
    for (int it = 0; it < 2; ++it)
        gload_lds16(kb_ + ksrc[it], &Ks[0][0] + kdst[it]);
    {
        float4 vv0 = *reinterpret_cast<const float4*>(vb_ + l * DK_ + vd8_0 * 8);
        float4 vv1 = *reinterpret_cast<const float4*>(vb_ + l * DK_ + vd8_1 * 8);
        const unsigned short* u0 = reinterpret_cast<const unsigned short*>(&vv0);
        const unsigned short* u1 = reinterpret_cast<const unsigned short*>(&vv1);
        #pragma unroll
        for (int s = 0; s < 8; ++s) {
            int d0 = vd8_0 * 8 + s;
            *reinterpret_cast<unsigned short*>(&Vt[0][0] + d0 * 128 +
                (((l >> 3) ^ (d0 & 7)) << 4) + (l & 7) * 2) = u0[s];
            int d1 = vd8_1 * 8 + s;
            *reinterpret_cast<unsigned short*>(&Vt[0][0] + d1 * 128 +
                (((l >> 3) ^ (d1 & 7)) << 4) + (l & 7) * 2) = u1[s];
        }
    }
    __syncthreads();

    for (int t = 0; t < nt; ++t) {
        const int cur = t & 1;
        const bool pre = (t + 1 < nt);
        float4 vv0, vv1;
        if (pre) {   // issue next-tile loads early (hide under compute)
            const size_t toff = (size_t)(t + 1) * 64 * DK_;
            #pragma unroll
            for (int it = 0; it < 2; ++it)
                gload_lds16(kb_ + toff + ksrc[it], &Ks[cur ^ 1][0] + kdst[it]);
            vv0 = *reinterpret_cast<const float4*>(vb_ + toff + l * DK_ + vd8_0 * 8);
            vv1 = *reinterpret_cast<const float4*>(vb_ + toff + l * DK_ + vd8_1 * 8);
        }

        // ---- S^T = K . Q^T ----
        f32x4 s_acc[4] = {};
        __builtin_amdgcn_s_setprio(1);
        #pragma unroll
        for (int jf = 0; jf < 4; ++jf) {
            int row = jf * 16 + i16;
            bf16x8 ak0 = *reinterpret_cast<const bf16x8*>(
                &Ks[cur][0] + row * 128 + ((g ^ (row & 7)) << 4));
            s_acc[jf] = __builtin_amdgcn_mfma_f32_16x16x32_bf16(
                ak0, qf0, s_acc[jf], 0, 0, 0);
            bf16x8 ak1 = *reinterpret_cast<const bf16x8*>(
                &Ks[cur][0] + row * 128 + (((4 + g) ^ (row & 7)) << 4));
            s_acc[jf] = __builtin_amdgcn_mfma_f32_16x16x32_bf16(
                ak1, qf1, s_acc[jf], 0, 0, 0);
        }
        __builtin_amdgcn_s_setprio(0);

        // ---- causal mask (diagonal tile only) ----
        if (t == nt - 1) {
            #pragma unroll
            for (int jf = 0; jf < 4; ++jf)
                #pragma unroll
                for (int r = 0; r < 4; ++r)
                    if (t * 64 + jf * 16 + g * 4 + r > qrow)
                        s_acc[jf][r] = -1e30f;
        }

        // ---- lane-local max (15 fmax, NO shfl) ----
        float mx0 = fmaxf(fmaxf(s_acc[0][0], s_acc[0][1]),
                          fmaxf(s_acc[0][2], s_acc[0][3]));
        float mx1 = fmaxf(fmaxf(s_acc[1][0], s_acc[1][1]),
                          fmaxf(s_acc[1][2], s_acc[1][3]));
        float mx2 = fmaxf(fmaxf(s_acc[2][0], s_acc[2][1]),
                          fmaxf(s_acc[2][2], s_acc[2][3]));
        float mx3 = fmaxf(fmaxf(s_acc[3][0], s_acc[3][1]),
                          fmaxf(s_acc[3][2], s_acc[3][3]));
        float vmax = fmaxf(fmaxf(mx0, mx1), fmaxf(mx2, mx3));

        // ---- defer-max: lane-local ballot; reduce+rescale only if needed ----
        if (!__all(vmax <= m_run + 11.5f)) {
            float rmax = fmaxf(vmax, __shfl_xor(vmax, 16, 64));
            rmax = fmaxf(rmax, __shfl_xor(rmax, 32, 64));
            float m_new = fmaxf(m_run, rmax);
            float factor = __builtin_amdgcn_exp2f(m_run - m_new);
            m_run = m_new;
            l_run *= factor;
            #pragma unroll
            for (int df = 0; df < 4; ++df)
                #pragma unroll
                for (int r = 0; r < 4; ++r)
                    o[df][r] *= factor;
        }

        // ---- P = exp2(S - m); per-lane partial row-sum as depth-4 tree ----
        float p[4][4];
        #pragma unroll
        for (int jf = 0; jf < 4; ++jf)
            #pragma unroll
            for (int r = 0; r < 4; ++r)
                p[jf][r] = __builtin_amdgcn_exp2f(s_acc[jf][r] - m_run);
        {
            float ps0 = (p[0][0] + p[0][1]) + (p[0][2] + p[0][3]);
            float ps1 = (p[1][0] + p[1][1]) + (p[1][2] + p[1][3]);
            float ps2 = (p[2][0] + p[2][1]) + (p[2][2] + p[2][3]);
            float ps3 = (p[3][0] + p[3][1]) + (p[3][2] + p[3][3]);
            l_run += (ps0 + ps1) + (ps2 + ps3);
        }

        // ---- pack P -> bf16, wave-local LDS (swizzled) ----
        #pragma unroll
        for (int jf = 0; jf < 4; ++jf)
            #pragma unroll
            for (int r0 = 0; r0 < 4; r0 += 2) {
                unsigned pk = pack2bf(p[jf][r0], p[jf][r0 + 1]);
                int jj = jf * 16 + g * 4 + r0;
                *reinterpret_cast<unsigned*>(pw + i16 * 128 +
                    ((jj * 2) ^ ((i16 & 7) << 4))) = pk;
            }

        // ---- O^T += V^T . P^T ----
        __builtin_amdgcn_s_setprio(1);
        #pragma unroll
        for (int jc = 0; jc < 2; ++jc) {
            bf16x8 bp = *reinterpret_cast<const bf16x8*>(pw + i16 * 128 +
                (((jc * 4 + g) ^ (i16 & 7)) << 4));
            #pragma unroll
            for (int df = 0; df < 4; ++df) {
                int row = df * 16 + i16;
                bf16x8 av = *reinterpret_cast<const bf16x8*>(
                    &Vt[cur][0] + row * 128 +
                    (((jc * 4 + g) ^ (row & 7)) << 4));
                o[df] = __builtin_amdgcn_mfma_f32_16x16x32_bf16(
                    av, bp, o[df], 0, 0, 0);
            }
        }
        __builtin_amdgcn_s_setprio(0);

        if (pre) {   // scatter-write next V^T after compute (conflict-free)
            unsigned char* vtb = &Vt[cur ^ 1][0];
            const unsigned short* u0 = reinterpret_cast<const unsigned short*>(&vv0);
            const unsigned short* u1 = reinterpret_cast<const unsigned short*>(&vv1);
            #pragma unroll
            for (int s = 0; s < 8; ++s) {
                int d0 = vd8_0 * 8 + s;
                *reinterpret_cast<unsigned short*>(vtb + d0 * 128 +
                    (((l >> 3) ^ (d0 & 7)) << 4) + (l & 7) * 2) = u0[s];
                int d1 = vd8_1 * 8 + s;
                *reinterpret_cast<unsigned short*>(vtb + d1 * 128 +
                    (((l >> 3) ^ (d1 & 7)) << 4) + (l & 7) * 2) = u1[s];
            }
        }
        __syncthreads();   // drains gload_lds (vmcnt) + LDS writes
    }

    // ---- epilogue: reduce per-lane l partials across row partners ----
    float l_tot = l_run;
    l_tot += __shfl_xor(l_tot, 16, 64);
    l_tot += __shfl_xor(l_tot, 32, 64);
    const float inv_l = 1.0f / l_tot;
    const int b_ = bh >> 4, h_ = bh & 15;
    __hip_bfloat16* orow = attn + ((size_t)b_ * S_ + qrow) * D_ + h_ * 64;
    #pragma unroll
    for (int df = 0; df < 4; ++df) {
        ushort4 uo = make_ushort4(
            bfbits(o[df][0] * inv_l), bfbits(o[df][1] * inv_l),
            bfbits(o[df][2] * inv_l), bfbits(o[df][3] * inv_l));
        *reinterpret_cast<ushort4*>(orow + df * 16 + g * 4) = uo;
    }
}

// ---------------------------------------------------------------------------
extern "C" void kernel_launch(void* const* d_in, const int* in_sizes, int n_in,
                              void* d_out, int out_size, void* d_ws, size_t ws_size,
                              hipStream_t stream) {
    const float* x       = (const float*)d_in[0];
    const float* w_q     = (const float*)d_in[1];
    const float* w_k     = (const float*)d_in[2];
    const float* w_v     = (const float*)d_in[3];
    const float* w_o     = (const float*)d_in[4];
    const float* sin_tab = (const float*)d_in[5];
    const float* cos_tab = (const float*)d_in[6];
    const int*   tpos    = (const int*)d_in[7];
    float* out = (float*)d_out;

    const size_t nM  = (size_t)B_ * S_ * D_;
    const size_t nW  = (size_t)D_ * D_;
    __hip_bfloat16* xb   = (__hip_bfloat16*)d_ws;
    __hip_bfloat16* wqb  = xb  + nM;
    __hip_bfloat16* wkb  = wqb + nW;
    __hip_bfloat16* wvb  = wkb + nW;
    __hip_bfloat16* wob  = wvb + nW;
    __hip_bfloat16* q_ws = wob + nW;
    __hip_bfloat16* k_ws = q_ws + nM;
    __hip_bfloat16* v_ws = k_ws + nM;
    __hip_bfloat16* a_ws = v_ws + nM;
    float2*         sct  = (float2*)(a_ws + nM);   // 65536 float2 = 512 KB

    to_bf16_kernel<<<dim3(1024, 9), 256, 0, stream>>>(
        x, w_q, w_k, w_v, w_o, sin_tab, cos_tab,
        xb, wqb, wkb, wvb, wob, sct);
    mfma_gemm_kernel<0><<<dim3(256, 1, 3), 256, 0, stream>>>(
        xb, wqb, wkb, wvb, q_ws, k_ws, v_ws, nullptr, sct, tpos);
    flash_mfma_kernel<<<1024, 256, 0, stream>>>(
        q_ws, k_ws, v_ws, a_ws);
    mfma_gemm_kernel<1><<<dim3(256, 1, 1), 256, 0, stream>>>(
        a_ws, wob, nullptr, nullptr, nullptr, nullptr, nullptr, out,
        sct, tpos);
}

// Round 15
// 119.752 us; speedup vs baseline: 1.1240x; 1.0046x over previous
//
#include <hip/hip_runtime.h>
#include <hip/hip_bf16.h>
#include <cstdint>

#define B_ 2
#define S_ 2048
#define D_ 1024
#define H_ 16
#define DK_ 64
#define HALF_ 32   // DK/2

typedef short bf16x8 __attribute__((ext_vector_type(8)));
typedef float f32x4  __attribute__((ext_vector_type(4)));
typedef unsigned int u32;

static __device__ __forceinline__ unsigned short bfbits(float f) {
    __hip_bfloat16 h = __float2bfloat16(f);
    unsigned short u; __builtin_memcpy(&u, &h, 2); return u;
}
static __device__ __forceinline__ unsigned pack2bf(float a, float b) {
    return (unsigned)bfbits(a) | ((unsigned)bfbits(b) << 16);
}

// async 16B global->LDS (wave-uniform LDS base + lane*16; global addr per-lane)
static __device__ __forceinline__ void gload_lds16(const void* g, void* l) {
    __builtin_amdgcn_global_load_lds(
        (const __attribute__((address_space(1))) u32*)(uintptr_t)g,
        (__attribute__((address_space(3))) u32*)(uintptr_t)l,
        16, 0, 0);
}

// ---------------------------------------------------------------------------
// Kernel 0: fp32 -> bf16 conversion (x + 4 weights) and packed (cos,sin) table.
// ---------------------------------------------------------------------------
__global__ __launch_bounds__(256) void to_bf16_kernel(
    const float* __restrict__ x,
    const float* __restrict__ wq, const float* __restrict__ wk,
    const float* __restrict__ wv, const float* __restrict__ wo,
    const float* __restrict__ sin_tab, const float* __restrict__ cos_tab,
    __hip_bfloat16* __restrict__ xb,
    __hip_bfloat16* __restrict__ wqb, __hip_bfloat16* __restrict__ wkb,
    __hip_bfloat16* __restrict__ wvb, __hip_bfloat16* __restrict__ wob,
    float2* __restrict__ sctab)
{
    const int seg = blockIdx.y;   // 0..3 x quarters; 4..7 weights; 8 sincos
    if (seg == 8) {
        if (blockIdx.x >= 64) return;     // 65536 entries / 4 per thread
        size_t i = ((size_t)blockIdx.x * 256 + threadIdx.x) * 4;
        float4 c = *reinterpret_cast<const float4*>(cos_tab + i);
        float4 s = *reinterpret_cast<const float4*>(sin_tab + i);
        float4* dst = reinterpret_cast<float4*>(sctab + i);
        dst[0] = make_float4(c.x, s.x, c.y, s.y);
        dst[1] = make_float4(c.z, s.z, c.w, s.w);
        return;
    }
    const float* src;
    __hip_bfloat16* dst;
    size_t off = 0;
    if (seg < 4)       { src = x;  dst = xb;  off = (size_t)seg << 20; }
    else if (seg == 4) { src = wq; dst = wqb; }
    else if (seg == 5) { src = wk; dst = wkb; }
    else if (seg == 6) { src = wv; dst = wvb; }
    else               { src = wo; dst = wob; }
    size_t i = off + ((size_t)blockIdx.x * 256 + threadIdx.x) * 4;
    float4 v = *reinterpret_cast<const float4*>(src + i);
    ushort4 u = make_ushort4(bfbits(v.x), bfbits(v.y), bfbits(v.z), bfbits(v.w));
    *reinterpret_cast<ushort4*>(dst + i) = u;
}

// ---------------------------------------------------------------------------
// MFMA GEMM v2 (round-10 proven): C = A @ W^T, bf16 in, 16x16x32,
// 128x128 tile, BK=32, dbuf, XCD swizzle.
// MODE 0: QKV + RoPE epilogue; Q pre-scaled by 0.125*log2(e). MODE 1: out-proj.
// ---------------------------------------------------------------------------
template<int MODE>
__global__ __launch_bounds__(256) void mfma_gemm_kernel(
    const __hip_bfloat16* __restrict__ A,
    const __hip_bfloat16* __restrict__ Wq, const __hip_bfloat16* __restrict__ Wk,
    const __hip_bfloat16* __restrict__ Wv,
    __hip_bfloat16* __restrict__ out_q, __hip_bfloat16* __restrict__ out_k,
    __hip_bfloat16* __restrict__ out_v,
    float* __restrict__ out_f32,
    const float2* __restrict__ sctab,
    const int* __restrict__ tpos)
{
    constexpr int K = 1024;
    const int which = (MODE == 0) ? blockIdx.z : 3;
    const __hip_bfloat16* __restrict__ W =
        (MODE == 1) ? Wq : (which == 0 ? Wq : which == 1 ? Wk : Wv);

    __shared__ __align__(16) unsigned char As[2][128 * 4 * 16];  // 2 x 8 KB
    __shared__ __align__(16) unsigned char Bs[2][128 * 4 * 16];  // 2 x 8 KB

    const int tid = threadIdx.x;
    const int wid = tid >> 6;
    const int l   = tid & 63;
    const int g   = l >> 4;
    const int i16 = l & 15;
    const int wr  = wid >> 1, wc = wid & 1;

    const int wg   = blockIdx.x;
    const int tile = (wg & 7) * 32 + (wg >> 3);
    const int row0 = (tile >> 3) * 128;
    const int col0 = (tile & 7) * 128;

    const __hip_bfloat16* Abase = A + (size_t)row0 * K;
    const __hip_bfloat16* Wbase = W + (size_t)col0 * K;

    f32x4 acc[4][4];
    const f32x4 zero = {0.f, 0.f, 0.f, 0.f};
    #pragma unroll
    for (int mi = 0; mi < 4; ++mi)
        #pragma unroll
        for (int ni = 0; ni < 4; ++ni) acc[mi][ni] = zero;

    int a_off[4], b_off[4];
    #pragma unroll
    for (int f = 0; f < 4; ++f) {
        int ra = wr * 64 + f * 16 + i16;
        a_off[f] = (ra * 4 + (g ^ ((ra >> 1) & 3))) * 16;
        int rb = wc * 64 + f * 16 + i16;
        b_off[f] = (rb * 4 + (g ^ ((rb >> 1) & 3))) * 16;
    }

    int st_goff[2], st_loff[2];
    #pragma unroll
    for (int it = 0; it < 2; ++it) {
        int c = it * 256 + wid * 64 + l;
        int row = c >> 2;
        int kc = (c & 3) ^ ((row >> 1) & 3);
        st_goff[it] = row * K + kc * 8;
        st_loff[it] = (it * 256 + wid * 64) * 16;
    }

    #pragma unroll
    for (int it = 0; it < 2; ++it) {
        gload_lds16(Abase + st_goff[it], &As[0][0] + st_loff[it]);
        gload_lds16(Wbase + st_goff[it], &Bs[0][0] + st_loff[it]);
    }
    __syncthreads();

    for (int t = 0; t < K / 32; ++t) {
        const int cur = t & 1;
        if (t + 1 < K / 32) {
            const int k1 = (t + 1) * 32;
            #pragma unroll
            for (int it = 0; it < 2; ++it) {
                gload_lds16(Abase + k1 + st_goff[it], &As[cur ^ 1][0] + st_loff[it]);
                gload_lds16(Wbase + k1 + st_goff[it], &Bs[cur ^ 1][0] + st_loff[it]);
            }
        }
        bf16x8 af[4], bfr[4];
        #pragma unroll
        for (int f = 0; f < 4; ++f) {
            af[f]  = *reinterpret_cast<const bf16x8*>(&As[cur][0] + a_off[f]);
            bfr[f] = *reinterpret_cast<const bf16x8*>(&Bs[cur][0] + b_off[f]);
        }
        #pragma unroll
        for (int mi = 0; mi < 4; ++mi)
            #pragma unroll
            for (int ni = 0; ni < 4; ++ni)
                acc[mi][ni] = __builtin_amdgcn_mfma_f32_16x16x32_bf16(
                    af[mi], bfr[ni], acc[mi][ni], 0, 0, 0);
        __syncthreads();
    }

    if (MODE == 0) {
        __hip_bfloat16* __restrict__ outp =
            which == 0 ? out_q : which == 1 ? out_k : out_v;
        const int head = (col0 >> 6) + wc;
        #pragma unroll
        for (int mi = 0; mi < 4; ++mi) {
            #pragma unroll
            for (int r = 0; r < 4; ++r) {
                const int gi = row0 + wr * 64 + mi * 16 + g * 4 + r;
                const int b_ = gi >> 11;
                const int s_ = gi & (S_ - 1);
                const int pos = tpos[gi];
                const float2* sc = sctab + pos * HALF_;
                __hip_bfloat16* orow =
                    outp + (((size_t)b_ * H_ + head) * S_ + s_) * DK_;
                #pragma unroll
                for (int ni = 0; ni < 4; ++ni) {
                    float val = acc[mi][ni][r];
                    const int dk = ni * 16 + i16;
                    float res;
                    if (which < 2) {   // block-uniform: V-blocks skip the shfl
                        float other = __shfl_xor(val, 1, 64);
                        float2 cs = sc[ni * 8 + (i16 >> 1)];
                        res = (i16 & 1) ? fmaf(cs.y, other, cs.x * val)
                                        : (cs.x * val - cs.y * other);
                    } else {
                        res = val;
                    }
                    // 0.125 * log2(e): softmax runs in exp2 domain
                    if (which == 0) res *= 0.180336880f;
                    orow[dk] = __float2bfloat16(res);
                }
            }
        }
    } else {
        #pragma unroll
        for (int mi = 0; mi < 4; ++mi) {
            #pragma unroll
            for (int r = 0; r < 4; ++r) {
                const int gi = row0 + wr * 64 + mi * 16 + g * 4 + r;
                float* orow = out_f32 + (size_t)gi * D_ + col0 + wc * 64;
                #pragma unroll
                for (int ni = 0; ni < 4; ++ni)
                    orow[ni * 16 + i16] = acc[mi][ni][r];
            }
        }
    }
}

// ---------------------------------------------------------------------------
// Kernel 2 (v7 = round-10 proven optimum): causal flash attention.
//  QBLK=64, 4 waves, 1024 blocks, balanced per-CU mapping, dbuf K
//  (gload_lds) + V^T (conflict-free reg scatter), shfl-free steady state
//  (lane-local defer-max ballot), deferred l-reduction, depth-4 psum tree.
//  Round-15 tweak: P-pack as 4 x 8B LDS writes (was 8 x 4B) — the two
//  dwords per jf stay adjacent under the XOR swizzle (swizzle flips byte
//  bit4; the pair differs in bit2), so a single aligned uint2 store works.
// ---------------------------------------------------------------------------
__global__ __launch_bounds__(256) void flash_mfma_kernel(
    const __hip_bfloat16* __restrict__ q,   // (b,h,s,dk), pre-scaled
    const __hip_bfloat16* __restrict__ k,
    const __hip_bfloat16* __restrict__ v,
    __hip_bfloat16* __restrict__ attn)      // (b,s,D) bf16
{
    __shared__ __align__(16) unsigned char Ks[2][64 * 128];  // 16 KB
    __shared__ __align__(16) unsigned char Vt[2][64 * 128];  // 16 KB
    __shared__ __align__(16) unsigned char Ps[4][16 * 128];  //  8 KB

    const int tid = threadIdx.x;
    const int w   = tid >> 6;        // 0..3
    const int l   = tid & 63;
    const int g   = l >> 4;
    const int i16 = l & 15;

    // balanced block swizzle: per-XCD bh locality; each CU's 4 blocks
    // (idx = r*32 + c, r=0..3) get qsb = {31-c, c, 31-c, c} -> 66 tiles total
    const int wgid = blockIdx.x;              // 0..1023
    const int xcd  = wgid & 7;
    const int idx  = wgid >> 3;               // 0..127
    const int r_   = idx >> 5;                // 0..3
    const int c_   = idx & 31;                // 0..31
    const int bh   = xcd * 4 + r_;
    const int qsb  = (r_ & 1) ? c_ : (31 - c_);

    const size_t base = (size_t)bh * S_ * DK_;
    const __hip_bfloat16* kb_ = k + base;
    const __hip_bfloat16* vb_ = v + base;
    const int nt = qsb + 1;

    // K staging geometry: 512 chunks of 16B, 2 per thread (linear LDS dest,
    // inverse swizzle folded into global source)
    int ksrc[2], kdst[2];
    #pragma unroll
    for (int it = 0; it < 2; ++it) {
        int c = it * 256 + tid;
        int krow = c >> 3;
        int kchunk = (c & 7) ^ (krow & 7);
        ksrc[it] = krow * DK_ + kchunk * 8;
        kdst[it] = c * 16;
    }
    // V staging: per-lane row j=l, wave-constant d8 (conflict-free, 2-way)
    const int vd8_0 = w;        // it = 0
    const int vd8_1 = 4 + w;    // it = 1
    unsigned char* const pw = &Ps[w][0];

    const int qrow = qsb * 64 + w * 16 + i16;  // this lane's q-row

    // Q fragments in registers
    bf16x8 qf0, qf1;
    {
        const __hip_bfloat16* qp = q + base + (size_t)qrow * DK_ + g * 8;
        qf0 = *reinterpret_cast<const bf16x8*>(qp);
        qf1 = *reinterpret_cast<const bf16x8*>(qp + 32);
    }

    f32x4 o[4] = {};
    float m_run = -1e30f, l_run = 0.0f;   // l_run = per-lane partial

    // prologue: stage tile 0 into buffer 0
    #pragma unroll
    for (int it = 0; it < 2; ++it)
        gload_lds16(kb_ + ksrc[it], &Ks[0][0] + kdst[it]);
    {
        float4 vv0 = *reinterpret_cast<const float4*>(vb_ + l * DK_ + vd8_0 * 8);
        float4 vv1 = *reinterpret_cast<const float4*>(vb_ + l * DK_ + vd8_1 * 8);
        const unsigned short* u0 = reinterpret_cast<const unsigned short*>(&vv0);
        const unsigned short* u1 = reinterpret_cast<const unsigned short*>(&vv1);
        #pragma unroll
        for (int s = 0; s < 8; ++s) {
            int d0 = vd8_0 * 8 + s;
            *reinterpret_cast<unsigned short*>(&Vt[0][0] + d0 * 128 +
                (((l >> 3) ^ (d0 & 7)) << 4) + (l & 7) * 2) = u0[s];
            int d1 = vd8_1 * 8 + s;
            *reinterpret_cast<unsigned short*>(&Vt[0][0] + d1 * 128 +
                (((l >> 3) ^ (d1 & 7)) << 4) + (l & 7) * 2) = u1[s];
        }
    }
    __syncthreads();

    for (int t = 0; t < nt; ++t) {
        const int cur = t & 1;
        const bool pre = (t + 1 < nt);
        float4 vv0, vv1;
        if (pre) {   // issue next-tile loads early (hide under compute)
            const size_t toff = (size_t)(t + 1) * 64 * DK_;
            #pragma unroll
            for (int it = 0; it < 2; ++it)
                gload_lds16(kb_ + toff + ksrc[it], &Ks[cur ^ 1][0] + kdst[it]);
            vv0 = *reinterpret_cast<const float4*>(vb_ + toff + l * DK_ + vd8_0 * 8);
            vv1 = *reinterpret_cast<const float4*>(vb_ + toff + l * DK_ + vd8_1 * 8);
        }

        // ---- S^T = K . Q^T ----
        f32x4 s_acc[4] = {};
        __builtin_amdgcn_s_setprio(1);
        #pragma unroll
        for (int jf = 0; jf < 4; ++jf) {
            int row = jf * 16 + i16;
            bf16x8 ak0 = *reinterpret_cast<const bf16x8*>(
                &Ks[cur][0] + row * 128 + ((g ^ (row & 7)) << 4));
            s_acc[jf] = __builtin_amdgcn_mfma_f32_16x16x32_bf16(
                ak0, qf0, s_acc[jf], 0, 0, 0);
            bf16x8 ak1 = *reinterpret_cast<const bf16x8*>(
                &Ks[cur][0] + row * 128 + (((4 + g) ^ (row & 7)) << 4));
            s_acc[jf] = __builtin_amdgcn_mfma_f32_16x16x32_bf16(
                ak1, qf1, s_acc[jf], 0, 0, 0);
        }
        __builtin_amdgcn_s_setprio(0);

        // ---- causal mask (diagonal tile only) ----
        if (t == nt - 1) {
            #pragma unroll
            for (int jf = 0; jf < 4; ++jf)
                #pragma unroll
                for (int r = 0; r < 4; ++r)
                    if (t * 64 + jf * 16 + g * 4 + r > qrow)
                        s_acc[jf][r] = -1e30f;
        }

        // ---- lane-local max (15 fmax, NO shfl) ----
        float mx0 = fmaxf(fmaxf(s_acc[0][0], s_acc[0][1]),
                          fmaxf(s_acc[0][2], s_acc[0][3]));
        float mx1 = fmaxf(fmaxf(s_acc[1][0], s_acc[1][1]),
                          fmaxf(s_acc[1][2], s_acc[1][3]));
        float mx2 = fmaxf(fmaxf(s_acc[2][0], s_acc[2][1]),
                          fmaxf(s_acc[2][2], s_acc[2][3]));
        float mx3 = fmaxf(fmaxf(s_acc[3][0], s_acc[3][1]),
                          fmaxf(s_acc[3][2], s_acc[3][3]));
        float vmax = fmaxf(fmaxf(mx0, mx1), fmaxf(mx2, mx3));

        // ---- defer-max: lane-local ballot; reduce+rescale only if needed ----
        if (!__all(vmax <= m_run + 11.5f)) {
            float rmax = fmaxf(vmax, __shfl_xor(vmax, 16, 64));
            rmax = fmaxf(rmax, __shfl_xor(rmax, 32, 64));
            float m_new = fmaxf(m_run, rmax);
            float factor = __builtin_amdgcn_exp2f(m_run - m_new);
            m_run = m_new;
            l_run *= factor;
            #pragma unroll
            for (int df = 0; df < 4; ++df)
                #pragma unroll
                for (int r = 0; r < 4; ++r)
                    o[df][r] *= factor;
        }

        // ---- P = exp2(S - m); per-lane partial row-sum as depth-4 tree ----
        float p[4][4];
        #pragma unroll
        for (int jf = 0; jf < 4; ++jf)
            #pragma unroll
            for (int r = 0; r < 4; ++r)
                p[jf][r] = __builtin_amdgcn_exp2f(s_acc[jf][r] - m_run);
        {
            float ps0 = (p[0][0] + p[0][1]) + (p[0][2] + p[0][3]);
            float ps1 = (p[1][0] + p[1][1]) + (p[1][2] + p[1][3]);
            float ps2 = (p[2][0] + p[2][1]) + (p[2][2] + p[2][3]);
            float ps3 = (p[3][0] + p[3][1]) + (p[3][2] + p[3][3]);
            l_run += (ps0 + ps1) + (ps2 + ps3);
        }

        // ---- pack P -> bf16, wave-local LDS: 4 x 8B writes (swizzled) ----
        #pragma unroll
        for (int jf = 0; jf < 4; ++jf) {
            uint2 pkv = make_uint2(pack2bf(p[jf][0], p[jf][1]),
                                   pack2bf(p[jf][2], p[jf][3]));
            int jj = jf * 16 + g * 4;
            *reinterpret_cast<uint2*>(pw + i16 * 128 +
                ((jj * 2) ^ ((i16 & 7) << 4))) = pkv;
        }

        // ---- O^T += V^T . P^T ----
        __builtin_amdgcn_s_setprio(1);
        #pragma unroll
        for (int jc = 0; jc < 2; ++jc) {
            bf16x8 bp = *reinterpret_cast<const bf16x8*>(pw + i16 * 128 +
                (((jc * 4 + g) ^ (i16 & 7)) << 4));
            #pragma unroll
            for (int df = 0; df < 4; ++df) {
                int row = df * 16 + i16;
                bf16x8 av = *reinterpret_cast<const bf16x8*>(
                    &Vt[cur][0] + row * 128 +
                    (((jc * 4 + g) ^ (row & 7)) << 4));
                o[df] = __builtin_amdgcn_mfma_f32_16x16x32_bf16(
                    av, bp, o[df], 0, 0, 0);
            }
        }
        __builtin_amdgcn_s_setprio(0);

        if (pre) {   // scatter-write next V^T after compute (conflict-free)
            unsigned char* vtb = &Vt[cur ^ 1][0];
            const unsigned short* u0 = reinterpret_cast<const unsigned short*>(&vv0);
            const unsigned short* u1 = reinterpret_cast<const unsigned short*>(&vv1);
            #pragma unroll
            for (int s = 0; s < 8; ++s) {
                int d0 = vd8_0 * 8 + s;
                *reinterpret_cast<unsigned short*>(vtb + d0 * 128 +
                    (((l >> 3) ^ (d0 & 7)) << 4) + (l & 7) * 2) = u0[s];
                int d1 = vd8_1 * 8 + s;
                *reinterpret_cast<unsigned short*>(vtb + d1 * 128 +
                    (((l >> 3) ^ (d1 & 7)) << 4) + (l & 7) * 2) = u1[s];
            }
        }
        __syncthreads();   // drains gload_lds (vmcnt) + LDS writes
    }

    // ---- epilogue: reduce per-lane l partials across row partners ----
    float l_tot = l_run;
    l_tot += __shfl_xor(l_tot, 16, 64);
    l_tot += __shfl_xor(l_tot, 32, 64);
    const float inv_l = 1.0f / l_tot;
    const int b_ = bh >> 4, h_ = bh & 15;
    __hip_bfloat16* orow = attn + ((size_t)b_ * S_ + qrow) * D_ + h_ * 64;
    #pragma unroll
    for (int df = 0; df < 4; ++df) {
        ushort4 uo = make_ushort4(
            bfbits(o[df][0] * inv_l), bfbits(o[df][1] * inv_l),
            bfbits(o[df][2] * inv_l), bfbits(o[df][3] * inv_l));
        *reinterpret_cast<ushort4*>(orow + df * 16 + g * 4) = uo;
    }
}

// ---------------------------------------------------------------------------
extern "C" void kernel_launch(void* const* d_in, const int* in_sizes, int n_in,
                              void* d_out, int out_size, void* d_ws, size_t ws_size,
                              hipStream_t stream) {
    const float* x       = (const float*)d_in[0];
    const float* w_q     = (const float*)d_in[1];
    const float* w_k     = (const float*)d_in[2];
    const float* w_v     = (const float*)d_in[3];
    const float* w_o     = (const float*)d_in[4];
    const float* sin_tab = (const float*)d_in[5];
    const float* cos_tab = (const float*)d_in[6];
    const int*   tpos    = (const int*)d_in[7];
    float* out = (float*)d_out;

    const size_t nM  = (size_t)B_ * S_ * D_;
    const size_t nW  = (size_t)D_ * D_;
    __hip_bfloat16* xb   = (__hip_bfloat16*)d_ws;
    __hip_bfloat16* wqb  = xb  + nM;
    __hip_bfloat16* wkb  = wqb + nW;
    __hip_bfloat16* wvb  = wkb + nW;
    __hip_bfloat16* wob  = wvb + nW;
    __hip_bfloat16* q_ws = wob + nW;
    __hip_bfloat16* k_ws = q_ws + nM;
    __hip_bfloat16* v_ws = k_ws + nM;
    __hip_bfloat16* a_ws = v_ws + nM;
    float2*         sct  = (float2*)(a_ws + nM);   // 65536 float2 = 512 KB

    to_bf16_kernel<<<dim3(1024, 9), 256, 0, stream>>>(
        x, w_q, w_k, w_v, w_o, sin_tab, cos_tab,
        xb, wqb, wkb, wvb, wob, sct);
    mfma_gemm_kernel<0><<<dim3(256, 1, 3), 256, 0, stream>>>(
        xb, wqb, wkb, wvb, q_ws, k_ws, v_ws, nullptr, sct, tpos);
    flash_mfma_kernel<<<1024, 256, 0, stream>>>(
        q_ws, k_ws, v_ws, a_ws);
    mfma_gemm_kernel<1><<<dim3(256, 1, 1), 256, 0, stream>>>(
        a_ws, wob, nullptr, nullptr, nullptr, nullptr, nullptr, out,
        sct, tpos);
}